// Round 4
// baseline (799.939 us; speedup 1.0000x reference)
//
#include <hip/hip_runtime.h>
#include <hip/hip_bf16.h>

// GCN 2-layer forward on MI355X (gfx950).
// DTYPES (per harness contract "per the reference"): x,W1,b1,W2,b2 = fp32;
// edge_index = int32 (confirmed: int64 read crashed OOB in round 1);
// d_out = fp32. Rounds 2-3 NaN = reading fp32 inputs as bf16 (low halves of
// fp32 have random exponent bits -> ~1/256 NaN rate).
//
// Pipeline: deg(int atomics) -> scan -> fill CSR | dinv
//   GEMM1(MFMA bf16, fp32->bf16 inline cvt, h1 bf16)
//   gather1(CSR, fp32 acc, +self+bias+relu -> r1 bf16)
//   GEMM2(MFMA, h2 bf16 reuses h1 buf)
//   gather2(CSR, +self+bias -> d_out fp32)

typedef __attribute__((ext_vector_type(8))) short bf16x8;   // 8 bf16 = 4 VGPRs
typedef __attribute__((ext_vector_type(4))) float f32x4;    // MFMA C/D

constexpr int NN = 100000;   // nodes
constexpr int NF = 512;      // input feats
constexpr int NH = 64;       // hidden
constexpr int NC = 40;       // classes
constexpr int NE = 1600000;  // edges
constexpr int NSCAN = (NN + 255) / 256;   // 391 scan blocks

// ---- ws layout (byte offsets; peak ~36MB) ----
constexpr size_t OFF_DEG    = 0;           // int deg -> fp32 dinv, in place
constexpr size_t OFF_ROWPTR = 524288;      // int[NN+1]
constexpr size_t OFF_CURSOR = 1048576;     // int[NN]
constexpr size_t OFF_BSUM   = 1572864;     // int[512] block sums
constexpr size_t OFF_EBUF   = 2097152;     // int[NE] bucketed src ids, 6.4MB
constexpr size_t OFF_H1     = 9437184;     // bf16[NN*64] = 12.8MB (h2 reuses)
constexpr size_t OFF_R1     = 23068672;    // bf16[NN*64] = 12.8MB

// fp32 -> bf16 (round-to-nearest) packed into MFMA fragment
__device__ inline short f2bs(float f) {
    union { __hip_bfloat16 h; short s; } u;
    u.h = __float2bfloat16(f);
    return u.s;
}
__device__ inline bf16x8 cvt8(const float* __restrict__ p) {
    bf16x8 r;
#pragma unroll
    for (int i = 0; i < 8; ++i) r[i] = f2bs(p[i]);
    return r;
}

// ---------------- degree ----------------
__global__ __launch_bounds__(256) void k_count_deg(const int* __restrict__ dst,
                                                   int* __restrict__ deg) {
    int e = blockIdx.x * 256 + threadIdx.x;
    if (e < NE) atomicAdd(&deg[dst[e]], 1);
}

// dinv[i] = 1/sqrt(deg+1), IN PLACE over int deg (runs after scan reads deg)
__global__ __launch_bounds__(256) void k_dinv(int* __restrict__ degi) {
    int i = blockIdx.x * 256 + threadIdx.x;
    if (i < NN) {
        float d = (float)degi[i] + 1.0f;   // +1 = self-loop
        ((float*)degi)[i] = 1.0f / sqrtf(d);
    }
}

// ---------------- 3-phase exclusive scan: deg -> rowptr ----------------
__global__ __launch_bounds__(256) void k_scan_a(const int* __restrict__ deg,
                                                int* __restrict__ rowptr,
                                                int* __restrict__ bsum) {
    __shared__ int s[256];
    int tid = threadIdx.x;
    int i = blockIdx.x * 256 + tid;
    int v = (i < NN) ? deg[i] : 0;
    s[tid] = v;
    __syncthreads();
    for (int off = 1; off < 256; off <<= 1) {
        int t = (tid >= off) ? s[tid - off] : 0;
        __syncthreads();
        s[tid] += t;
        __syncthreads();
    }
    if (i < NN) rowptr[i] = s[tid] - v;          // local exclusive
    if (tid == 255) bsum[blockIdx.x] = s[255];   // block total
}

__global__ __launch_bounds__(512) void k_scan_b(int* __restrict__ bsum) {
    __shared__ int s[512];
    int tid = threadIdx.x;
    int v = (tid < NSCAN) ? bsum[tid] : 0;
    s[tid] = v;
    __syncthreads();
    for (int off = 1; off < 512; off <<= 1) {
        int t = (tid >= off) ? s[tid - off] : 0;
        __syncthreads();
        s[tid] += t;
        __syncthreads();
    }
    if (tid < NSCAN) bsum[tid] = s[tid] - v;     // exclusive block prefix
}

__global__ __launch_bounds__(256) void k_scan_c(int* __restrict__ rowptr,
                                                int* __restrict__ cursor,
                                                const int* __restrict__ bsum) {
    int i = blockIdx.x * 256 + threadIdx.x;
    if (i < NN) {
        int r = rowptr[i] + bsum[blockIdx.x];
        rowptr[i] = r;
        cursor[i] = r;
    }
    if (i == 0) rowptr[NN] = NE;
}

// ---------------- bucket fill: ebuf[rowptr[d]..] = src ids ----------------
__global__ __launch_bounds__(256) void k_fill(const int* __restrict__ src,
                                              const int* __restrict__ dst,
                                              int* __restrict__ cursor,
                                              int* __restrict__ ebuf) {
    int e = blockIdx.x * 256 + threadIdx.x;
    if (e < NE) {
        int p = atomicAdd(&cursor[dst[e]], 1);
        ebuf[p] = src[e];
    }
}

// ---------------- GEMM1: h1[NN,64] = x[NN,512] @ W1[64,512]^T (bf16 out) ----
// One wave: 64 rows x 64 cols, 4x4 tiles of 16x16x32 MFMA. fp32 inputs
// converted to bf16 inline. Layouts (m89/m91): A lane holds A[m=lane&15]
// [k=q*8+j]; B lane n+16q holds B[q*8+j][n]; C/D row=q*4+reg, col=lane&15.
__global__ __launch_bounds__(256) void k_gemm1(const float* __restrict__ x,
                                               const float* __restrict__ W1,
                                               __hip_bfloat16* __restrict__ h1) {
    const int lane = threadIdx.x & 63;
    const int wave = blockIdx.x * 4 + (threadIdx.x >> 6);
    const int row0 = wave * 64;
    if (row0 >= NN) return;
    const int q = lane >> 4, m = lane & 15;

    f32x4 acc[4][4];
#pragma unroll
    for (int i = 0; i < 4; ++i)
#pragma unroll
        for (int j = 0; j < 4; ++j) acc[i][j] = (f32x4){0.f, 0.f, 0.f, 0.f};

    for (int k0 = 0; k0 < NF; k0 += 32) {
        bf16x8 bfr[4];
#pragma unroll
        for (int ot = 0; ot < 4; ++ot)
            bfr[ot] = cvt8(W1 + (ot * 16 + m) * NF + k0 + q * 8);
#pragma unroll
        for (int mt = 0; mt < 4; ++mt) {
            int r = row0 + mt * 16 + m;
            if (r > NN - 1) r = NN - 1;  // tail clamp (store guarded)
            bf16x8 afr = cvt8(x + (size_t)r * NF + k0 + q * 8);
#pragma unroll
            for (int ot = 0; ot < 4; ++ot)
                acc[mt][ot] = __builtin_amdgcn_mfma_f32_16x16x32_bf16(afr, bfr[ot], acc[mt][ot], 0, 0, 0);
        }
    }

#pragma unroll
    for (int mt = 0; mt < 4; ++mt)
#pragma unroll
        for (int rr = 0; rr < 4; ++rr) {
            int row = row0 + mt * 16 + q * 4 + rr;
            if (row < NN) {
#pragma unroll
                for (int ot = 0; ot < 4; ++ot)
                    h1[row * NH + ot * 16 + m] = __float2bfloat16(acc[mt][ot][rr]);
            }
        }
}

// ---------------- gather1: r1[n] = relu(sum_bucket + self + b1) ----------------
// one wave per node; lane = feature (64).
__global__ __launch_bounds__(256) void k_gather1(const int* __restrict__ rowptr,
                                                 const int* __restrict__ ebuf,
                                                 const float* __restrict__ dinv,
                                                 const __hip_bfloat16* __restrict__ h1,
                                                 const float* __restrict__ b1,
                                                 __hip_bfloat16* __restrict__ r1) {
    const int lane = threadIdx.x & 63;
    const int n = blockIdx.x * 4 + (threadIdx.x >> 6);
    if (n >= NN) return;
    const float dn = dinv[n];
    float acc = 0.0f;
    const int beg = rowptr[n], end = rowptr[n + 1];
    for (int j = beg; j < end; ++j) {
        int s = ebuf[j];
        float w = dinv[s] * dn;
        acc += __bfloat162float(h1[s * NH + lane]) * w;
    }
    acc += dn * dn * __bfloat162float(h1[n * NH + lane]) + b1[lane];
    r1[n * NH + lane] = __float2bfloat16(fmaxf(acc, 0.0f));
}

// ---------------- GEMM2: h2[NN,40] = r1[NN,64] @ W2[40,64]^T (bf16 out) ----
__global__ __launch_bounds__(256) void k_gemm2(const __hip_bfloat16* __restrict__ r1,
                                               const float* __restrict__ W2,
                                               __hip_bfloat16* __restrict__ h2) {
    const int lane = threadIdx.x & 63;
    const int wave = blockIdx.x * 4 + (threadIdx.x >> 6);
    const int row0 = wave * 64;
    if (row0 >= NN) return;
    const int q = lane >> 4, m = lane & 15;

    f32x4 acc[4][3];
#pragma unroll
    for (int i = 0; i < 4; ++i)
#pragma unroll
        for (int j = 0; j < 3; ++j) acc[i][j] = (f32x4){0.f, 0.f, 0.f, 0.f};

#pragma unroll
    for (int k0 = 0; k0 < NH; k0 += 32) {
        bf16x8 bfr[3];
#pragma unroll
        for (int ot = 0; ot < 3; ++ot) {
            int o = ot * 16 + m;
            if (o > NC - 1) o = NC - 1;  // stay inside W2's 40 rows
            bfr[ot] = cvt8(W2 + o * NH + k0 + q * 8);
        }
#pragma unroll
        for (int mt = 0; mt < 4; ++mt) {
            int r = row0 + mt * 16 + m;
            if (r > NN - 1) r = NN - 1;
            bf16x8 afr = *reinterpret_cast<const bf16x8*>(r1 + r * NH + k0 + q * 8);
#pragma unroll
            for (int ot = 0; ot < 3; ++ot)
                acc[mt][ot] = __builtin_amdgcn_mfma_f32_16x16x32_bf16(afr, bfr[ot], acc[mt][ot], 0, 0, 0);
        }
    }

#pragma unroll
    for (int mt = 0; mt < 4; ++mt)
#pragma unroll
        for (int rr = 0; rr < 4; ++rr) {
            int row = row0 + mt * 16 + q * 4 + rr;
            if (row < NN) {
#pragma unroll
                for (int ot = 0; ot < 3; ++ot) {
                    int col = ot * 16 + m;
                    if (col < NC) h2[row * NC + col] = __float2bfloat16(acc[mt][ot][rr]);
                }
            }
        }
}

// ---------------- gather2: out[n] = sum_bucket + self + b2 (fp32 out) -------
// one wave per node; lanes 0..39 = classes.
__global__ __launch_bounds__(256) void k_gather2(const int* __restrict__ rowptr,
                                                 const int* __restrict__ ebuf,
                                                 const float* __restrict__ dinv,
                                                 const __hip_bfloat16* __restrict__ h2,
                                                 const float* __restrict__ b2,
                                                 float* __restrict__ out) {
    const int lane = threadIdx.x & 63;
    const int n = blockIdx.x * 4 + (threadIdx.x >> 6);
    if (n >= NN || lane >= NC) return;
    const float dn = dinv[n];
    float acc = 0.0f;
    const int beg = rowptr[n], end = rowptr[n + 1];
    for (int j = beg; j < end; ++j) {
        int s = ebuf[j];
        float w = dinv[s] * dn;
        acc += __bfloat162float(h2[s * NC + lane]) * w;
    }
    acc += dn * dn * __bfloat162float(h2[n * NC + lane]) + b2[lane];
    out[n * NC + lane] = acc;
}

extern "C" void kernel_launch(void* const* d_in, const int* in_sizes, int n_in,
                              void* d_out, int out_size, void* d_ws, size_t ws_size,
                              hipStream_t stream) {
    const float* x  = (const float*)d_in[0];
    const int*   ei = (const int*)d_in[1];   // int64 in ref -> int32 on device
    const float* W1 = (const float*)d_in[2];
    const float* b1 = (const float*)d_in[3];
    const float* W2 = (const float*)d_in[4];
    const float* b2 = (const float*)d_in[5];
    const int* srcp = ei;        // edge_index[0]
    const int* dstp = ei + NE;   // edge_index[1]

    char* ws = (char*)d_ws;
    int*            degi   = (int*)(ws + OFF_DEG);
    float*          dinv   = (float*)(ws + OFF_DEG);
    int*            rowptr = (int*)(ws + OFF_ROWPTR);
    int*            cursor = (int*)(ws + OFF_CURSOR);
    int*            bsum   = (int*)(ws + OFF_BSUM);
    int*            ebuf   = (int*)(ws + OFF_EBUF);
    __hip_bfloat16* h1     = (__hip_bfloat16*)(ws + OFF_H1);  // h2 reuses this
    __hip_bfloat16* r1     = (__hip_bfloat16*)(ws + OFF_R1);

    // --- CSR build (shared by both layers) ---
    hipMemsetAsync(degi, 0, (size_t)NN * sizeof(int), stream);
    k_count_deg<<<(NE + 255) / 256, 256, 0, stream>>>(dstp, degi);
    k_scan_a<<<NSCAN, 256, 0, stream>>>(degi, rowptr, bsum);
    k_scan_b<<<1, 512, 0, stream>>>(bsum);
    k_scan_c<<<NSCAN, 256, 0, stream>>>(rowptr, cursor, bsum);
    k_dinv<<<NSCAN, 256, 0, stream>>>(degi);           // after scan_a read deg
    k_fill<<<(NE + 255) / 256, 256, 0, stream>>>(srcp, dstp, cursor, ebuf);

    const int gemm_blocks = (NN + 255) / 256;   // 4 waves/block, 64 rows/wave
    const int node_blocks = (NN + 3) / 4;       // 4 waves/block, 1 node/wave

    // --- layer 1 ---
    k_gemm1<<<gemm_blocks, 256, 0, stream>>>(x, W1, h1);
    k_gather1<<<node_blocks, 256, 0, stream>>>(rowptr, ebuf, dinv, h1, b1, r1);

    // --- layer 2 (h2 reuses h1's buffer) ---
    __hip_bfloat16* h2 = h1;
    k_gemm2<<<gemm_blocks, 256, 0, stream>>>(r1, W2, h2);
    k_gather2<<<node_blocks, 256, 0, stream>>>(rowptr, ebuf, dinv, h2, b2,
                                               (float*)d_out);
}

// Round 5
// 646.917 us; speedup vs baseline: 1.2365x; 1.2365x over previous
//
#include <hip/hip_runtime.h>
#include <hip/hip_bf16.h>

// GCN 2-layer forward on MI355X (gfx950). fp32 in/out, int32 edges.
// Round 5: gather kernels were latency-bound (148us, 8.7% HBM, FETCH=88MB on
// 20MB unique -> per-XCD L2 thrash, serial dependent loads). Fixes:
//  (a) h1s/h2s stored pre-scaled by dinv[row] -> no per-edge dinv load;
//      sum factors as out = dn * (sum_s h1s[s] + h1s[n]) + b.
//  (b) 8-edge batched gather: 8 independent id loads then 8 independent row
//      loads -> dependent chain ~2 latencies per chunk instead of 2 per edge.
//  (c) W1/W2 pre-converted to bf16 once (k_cvtw) -> GEMMs skip B-side cvt.

typedef __attribute__((ext_vector_type(8))) short bf16x8;   // 8 bf16 = 4 VGPRs
typedef __attribute__((ext_vector_type(4))) float f32x4;    // MFMA C/D

constexpr int NN = 100000;   // nodes
constexpr int NF = 512;      // input feats
constexpr int NH = 64;       // hidden
constexpr int NC = 40;       // classes
constexpr int NE = 1600000;  // edges
constexpr int NSCAN = (NN + 255) / 256;   // 391 scan blocks

// ---- ws layout (byte offsets; peak ~36MB) ----
constexpr size_t OFF_DEG    = 0;           // int deg -> fp32 dinv, in place
constexpr size_t OFF_ROWPTR = 524288;      // int[NN+1]
constexpr size_t OFF_CURSOR = 1048576;     // int[NN]
constexpr size_t OFF_BSUM   = 1572864;     // int[512]
constexpr size_t OFF_W1BF   = 1576960;     // bf16[64*512] = 64KB
constexpr size_t OFF_W2BF   = 1642496;     // bf16[40*64]
constexpr size_t OFF_EBUF   = 2097152;     // int[NE] bucketed src ids, 6.4MB
constexpr size_t OFF_H1     = 9437184;     // bf16[NN*64] = 12.8MB (h2s reuses)
constexpr size_t OFF_R1     = 23068672;    // bf16[NN*64] = 12.8MB

// fp32 -> bf16 fragment helpers
__device__ inline short f2bs(float f) {
    union { __hip_bfloat16 h; short s; } u;
    u.h = __float2bfloat16(f);
    return u.s;
}
__device__ inline bf16x8 cvt8(const float* __restrict__ p) {
    bf16x8 r;
#pragma unroll
    for (int i = 0; i < 8; ++i) r[i] = f2bs(p[i]);
    return r;
}

// ---------------- degree ----------------
__global__ __launch_bounds__(256) void k_count_deg(const int* __restrict__ dst,
                                                   int* __restrict__ deg) {
    int e = blockIdx.x * 256 + threadIdx.x;
    if (e < NE) atomicAdd(&deg[dst[e]], 1);
}

// dinv[i] = 1/sqrt(deg+1), IN PLACE over int deg (runs after scan reads deg)
__global__ __launch_bounds__(256) void k_dinv(int* __restrict__ degi) {
    int i = blockIdx.x * 256 + threadIdx.x;
    if (i < NN) {
        float d = (float)degi[i] + 1.0f;   // +1 = self-loop
        ((float*)degi)[i] = 1.0f / sqrtf(d);
    }
}

// ---------------- W1/W2 fp32 -> bf16 (once) ----------------
__global__ __launch_bounds__(256) void k_cvtw(const float* __restrict__ W1,
                                              const float* __restrict__ W2,
                                              __hip_bfloat16* __restrict__ W1bf,
                                              __hip_bfloat16* __restrict__ W2bf) {
    int i = blockIdx.x * 256 + threadIdx.x;
    if (i < NH * NF) W1bf[i] = __float2bfloat16(W1[i]);
    int j = i - NH * NF;
    if (j >= 0 && j < NC * NH) W2bf[j] = __float2bfloat16(W2[j]);
}

// ---------------- 3-phase exclusive scan: deg -> rowptr ----------------
__global__ __launch_bounds__(256) void k_scan_a(const int* __restrict__ deg,
                                                int* __restrict__ rowptr,
                                                int* __restrict__ bsum) {
    __shared__ int s[256];
    int tid = threadIdx.x;
    int i = blockIdx.x * 256 + tid;
    int v = (i < NN) ? deg[i] : 0;
    s[tid] = v;
    __syncthreads();
    for (int off = 1; off < 256; off <<= 1) {
        int t = (tid >= off) ? s[tid - off] : 0;
        __syncthreads();
        s[tid] += t;
        __syncthreads();
    }
    if (i < NN) rowptr[i] = s[tid] - v;          // local exclusive
    if (tid == 255) bsum[blockIdx.x] = s[255];   // block total
}

__global__ __launch_bounds__(512) void k_scan_b(int* __restrict__ bsum) {
    __shared__ int s[512];
    int tid = threadIdx.x;
    int v = (tid < NSCAN) ? bsum[tid] : 0;
    s[tid] = v;
    __syncthreads();
    for (int off = 1; off < 512; off <<= 1) {
        int t = (tid >= off) ? s[tid - off] : 0;
        __syncthreads();
        s[tid] += t;
        __syncthreads();
    }
    if (tid < NSCAN) bsum[tid] = s[tid] - v;     // exclusive block prefix
}

__global__ __launch_bounds__(256) void k_scan_c(int* __restrict__ rowptr,
                                                int* __restrict__ cursor,
                                                const int* __restrict__ bsum) {
    int i = blockIdx.x * 256 + threadIdx.x;
    if (i < NN) {
        int r = rowptr[i] + bsum[blockIdx.x];
        rowptr[i] = r;
        cursor[i] = r;
    }
    if (i == 0) rowptr[NN] = NE;
}

// ---------------- bucket fill: ebuf[rowptr[d]..] = src ids ----------------
__global__ __launch_bounds__(256) void k_fill(const int* __restrict__ src,
                                              const int* __restrict__ dst,
                                              int* __restrict__ cursor,
                                              int* __restrict__ ebuf) {
    int e = blockIdx.x * 256 + threadIdx.x;
    if (e < NE) {
        int p = atomicAdd(&cursor[dst[e]], 1);
        ebuf[p] = src[e];
    }
}

// ---------------- GEMM1: h1s[NN,64] = (x @ W1^T) * dinv[row]  (bf16) ----
// One wave: 64 rows x 64 cols, 4x4 tiles of 16x16x32 MFMA. A-side fp32->bf16
// inline; B-side pre-converted bf16. Layouts (m89/m91): A[m=lane&15][k=q*8+j];
// C/D row=q*4+reg, col=lane&15.
__global__ __launch_bounds__(256) void k_gemm1(const float* __restrict__ x,
                                               const __hip_bfloat16* __restrict__ W1bf,
                                               const float* __restrict__ dinv,
                                               __hip_bfloat16* __restrict__ h1s) {
    const int lane = threadIdx.x & 63;
    const int wave = blockIdx.x * 4 + (threadIdx.x >> 6);
    const int row0 = wave * 64;
    if (row0 >= NN) return;
    const int q = lane >> 4, m = lane & 15;

    f32x4 acc[4][4];
#pragma unroll
    for (int i = 0; i < 4; ++i)
#pragma unroll
        for (int j = 0; j < 4; ++j) acc[i][j] = (f32x4){0.f, 0.f, 0.f, 0.f};

    for (int k0 = 0; k0 < NF; k0 += 32) {
        bf16x8 bfr[4];
#pragma unroll
        for (int ot = 0; ot < 4; ++ot)
            bfr[ot] = *reinterpret_cast<const bf16x8*>(W1bf + (ot * 16 + m) * NF + k0 + q * 8);
#pragma unroll
        for (int mt = 0; mt < 4; ++mt) {
            int r = row0 + mt * 16 + m;
            if (r > NN - 1) r = NN - 1;  // tail clamp (store guarded)
            bf16x8 afr = cvt8(x + (size_t)r * NF + k0 + q * 8);
#pragma unroll
            for (int ot = 0; ot < 4; ++ot)
                acc[mt][ot] = __builtin_amdgcn_mfma_f32_16x16x32_bf16(afr, bfr[ot], acc[mt][ot], 0, 0, 0);
        }
    }

#pragma unroll
    for (int mt = 0; mt < 4; ++mt)
#pragma unroll
        for (int rr = 0; rr < 4; ++rr) {
            int row = row0 + mt * 16 + q * 4 + rr;
            if (row < NN) {
                float di = dinv[row];
#pragma unroll
                for (int ot = 0; ot < 4; ++ot)
                    h1s[row * NH + ot * 16 + m] = __float2bfloat16(acc[mt][ot][rr] * di);
            }
        }
}

// ---------------- gather1: r1[n] = relu(dn * (sum h1s[s] + h1s[n]) + b1) ----
// one wave per node; lane = feature. 8-edge chunks for memory-level parallelism.
__global__ __launch_bounds__(256) void k_gather1(const int* __restrict__ rowptr,
                                                 const int* __restrict__ ebuf,
                                                 const float* __restrict__ dinv,
                                                 const __hip_bfloat16* __restrict__ h1s,
                                                 const float* __restrict__ b1,
                                                 __hip_bfloat16* __restrict__ r1) {
    const int lane = threadIdx.x & 63;
    const int n = blockIdx.x * 4 + (threadIdx.x >> 6);
    if (n >= NN) return;
    const int beg = rowptr[n], end = rowptr[n + 1];
    float acc = 0.0f;
    int j = beg;
    for (; j + 8 <= end; j += 8) {
        int e0 = ebuf[j + 0], e1 = ebuf[j + 1], e2 = ebuf[j + 2], e3 = ebuf[j + 3];
        int e4 = ebuf[j + 4], e5 = ebuf[j + 5], e6 = ebuf[j + 6], e7 = ebuf[j + 7];
        float v0 = __bfloat162float(h1s[e0 * NH + lane]);
        float v1 = __bfloat162float(h1s[e1 * NH + lane]);
        float v2 = __bfloat162float(h1s[e2 * NH + lane]);
        float v3 = __bfloat162float(h1s[e3 * NH + lane]);
        float v4 = __bfloat162float(h1s[e4 * NH + lane]);
        float v5 = __bfloat162float(h1s[e5 * NH + lane]);
        float v6 = __bfloat162float(h1s[e6 * NH + lane]);
        float v7 = __bfloat162float(h1s[e7 * NH + lane]);
        acc += ((v0 + v1) + (v2 + v3)) + ((v4 + v5) + (v6 + v7));
    }
    for (; j < end; ++j)
        acc += __bfloat162float(h1s[ebuf[j] * NH + lane]);
    acc += __bfloat162float(h1s[n * NH + lane]);   // self-loop (pre-scaled)
    acc = acc * dinv[n] + b1[lane];
    r1[n * NH + lane] = __float2bfloat16(fmaxf(acc, 0.0f));
}

// ---------------- GEMM2: h2s[NN,40] = (r1 @ W2^T) * dinv[row]  (bf16) ----
__global__ __launch_bounds__(256) void k_gemm2(const __hip_bfloat16* __restrict__ r1,
                                               const __hip_bfloat16* __restrict__ W2bf,
                                               const float* __restrict__ dinv,
                                               __hip_bfloat16* __restrict__ h2s) {
    const int lane = threadIdx.x & 63;
    const int wave = blockIdx.x * 4 + (threadIdx.x >> 6);
    const int row0 = wave * 64;
    if (row0 >= NN) return;
    const int q = lane >> 4, m = lane & 15;

    f32x4 acc[4][3];
#pragma unroll
    for (int i = 0; i < 4; ++i)
#pragma unroll
        for (int j = 0; j < 3; ++j) acc[i][j] = (f32x4){0.f, 0.f, 0.f, 0.f};

#pragma unroll
    for (int k0 = 0; k0 < NH; k0 += 32) {
        bf16x8 bfr[3];
#pragma unroll
        for (int ot = 0; ot < 3; ++ot) {
            int o = ot * 16 + m;
            if (o > NC - 1) o = NC - 1;  // stay inside W2's 40 rows
            bfr[ot] = *reinterpret_cast<const bf16x8*>(W2bf + o * NH + k0 + q * 8);
        }
#pragma unroll
        for (int mt = 0; mt < 4; ++mt) {
            int r = row0 + mt * 16 + m;
            if (r > NN - 1) r = NN - 1;
            bf16x8 afr = *reinterpret_cast<const bf16x8*>(r1 + r * NH + k0 + q * 8);
#pragma unroll
            for (int ot = 0; ot < 3; ++ot)
                acc[mt][ot] = __builtin_amdgcn_mfma_f32_16x16x32_bf16(afr, bfr[ot], acc[mt][ot], 0, 0, 0);
        }
    }

#pragma unroll
    for (int mt = 0; mt < 4; ++mt)
#pragma unroll
        for (int rr = 0; rr < 4; ++rr) {
            int row = row0 + mt * 16 + q * 4 + rr;
            if (row < NN) {
                float di = dinv[row];
#pragma unroll
                for (int ot = 0; ot < 3; ++ot) {
                    int col = ot * 16 + m;
                    if (col < NC) h2s[row * NC + col] = __float2bfloat16(acc[mt][ot][rr] * di);
                }
            }
        }
}

// ---------------- gather2: out[n] = dn*(sum h2s[s] + h2s[n]) + b2 (fp32) ----
__global__ __launch_bounds__(256) void k_gather2(const int* __restrict__ rowptr,
                                                 const int* __restrict__ ebuf,
                                                 const float* __restrict__ dinv,
                                                 const __hip_bfloat16* __restrict__ h2s,
                                                 const float* __restrict__ b2,
                                                 float* __restrict__ out) {
    const int lane = threadIdx.x & 63;
    const int n = blockIdx.x * 4 + (threadIdx.x >> 6);
    if (n >= NN || lane >= NC) return;
    const int beg = rowptr[n], end = rowptr[n + 1];
    float acc = 0.0f;
    int j = beg;
    for (; j + 8 <= end; j += 8) {
        int e0 = ebuf[j + 0], e1 = ebuf[j + 1], e2 = ebuf[j + 2], e3 = ebuf[j + 3];
        int e4 = ebuf[j + 4], e5 = ebuf[j + 5], e6 = ebuf[j + 6], e7 = ebuf[j + 7];
        float v0 = __bfloat162float(h2s[e0 * NC + lane]);
        float v1 = __bfloat162float(h2s[e1 * NC + lane]);
        float v2 = __bfloat162float(h2s[e2 * NC + lane]);
        float v3 = __bfloat162float(h2s[e3 * NC + lane]);
        float v4 = __bfloat162float(h2s[e4 * NC + lane]);
        float v5 = __bfloat162float(h2s[e5 * NC + lane]);
        float v6 = __bfloat162float(h2s[e6 * NC + lane]);
        float v7 = __bfloat162float(h2s[e7 * NC + lane]);
        acc += ((v0 + v1) + (v2 + v3)) + ((v4 + v5) + (v6 + v7));
    }
    for (; j < end; ++j)
        acc += __bfloat162float(h2s[ebuf[j] * NC + lane]);
    acc += __bfloat162float(h2s[n * NC + lane]);   // self-loop (pre-scaled)
    out[n * NC + lane] = acc * dinv[n] + b2[lane];
}

extern "C" void kernel_launch(void* const* d_in, const int* in_sizes, int n_in,
                              void* d_out, int out_size, void* d_ws, size_t ws_size,
                              hipStream_t stream) {
    const float* x  = (const float*)d_in[0];
    const int*   ei = (const int*)d_in[1];
    const float* W1 = (const float*)d_in[2];
    const float* b1 = (const float*)d_in[3];
    const float* W2 = (const float*)d_in[4];
    const float* b2 = (const float*)d_in[5];
    const int* srcp = ei;        // edge_index[0]
    const int* dstp = ei + NE;   // edge_index[1]

    char* ws = (char*)d_ws;
    int*            degi   = (int*)(ws + OFF_DEG);
    float*          dinv   = (float*)(ws + OFF_DEG);
    int*            rowptr = (int*)(ws + OFF_ROWPTR);
    int*            cursor = (int*)(ws + OFF_CURSOR);
    int*            bsum   = (int*)(ws + OFF_BSUM);
    __hip_bfloat16* W1bf   = (__hip_bfloat16*)(ws + OFF_W1BF);
    __hip_bfloat16* W2bf   = (__hip_bfloat16*)(ws + OFF_W2BF);
    int*            ebuf   = (int*)(ws + OFF_EBUF);
    __hip_bfloat16* h1s    = (__hip_bfloat16*)(ws + OFF_H1);  // h2s reuses
    __hip_bfloat16* r1     = (__hip_bfloat16*)(ws + OFF_R1);

    // --- weights to bf16 (independent of CSR) ---
    k_cvtw<<<(NH * NF + NC * NH + 255) / 256, 256, 0, stream>>>(W1, W2, W1bf, W2bf);

    // --- CSR build (shared by both layers) ---
    hipMemsetAsync(degi, 0, (size_t)NN * sizeof(int), stream);
    k_count_deg<<<(NE + 255) / 256, 256, 0, stream>>>(dstp, degi);
    k_scan_a<<<NSCAN, 256, 0, stream>>>(degi, rowptr, bsum);
    k_scan_b<<<1, 512, 0, stream>>>(bsum);
    k_scan_c<<<NSCAN, 256, 0, stream>>>(rowptr, cursor, bsum);
    k_dinv<<<NSCAN, 256, 0, stream>>>(degi);           // after scan_a read deg
    k_fill<<<(NE + 255) / 256, 256, 0, stream>>>(srcp, dstp, cursor, ebuf);

    const int gemm_blocks = (NN + 255) / 256;   // 4 waves/block, 64 rows/wave
    const int node_blocks = (NN + 3) / 4;       // 4 waves/block, 1 node/wave

    // --- layer 1 ---
    k_gemm1<<<gemm_blocks, 256, 0, stream>>>(x, W1bf, dinv, h1s);
    k_gather1<<<node_blocks, 256, 0, stream>>>(rowptr, ebuf, dinv, h1s, b1, r1);

    // --- layer 2 (h2s reuses h1s's buffer) ---
    __hip_bfloat16* h2s = h1s;
    k_gemm2<<<gemm_blocks, 256, 0, stream>>>(r1, W2bf, dinv, h2s);
    k_gather2<<<node_blocks, 256, 0, stream>>>(rowptr, ebuf, dinv, h2s, b2,
                                               (float*)d_out);
}

// Round 6
// 504.918 us; speedup vs baseline: 1.5843x; 1.2812x over previous
//
#include <hip/hip_runtime.h>
#include <hip/hip_bf16.h>

// GCN 2-layer forward on MI355X (gfx950). fp32 in/out, int32 edges.
// Round 6: k_fill was writeback-amplification-bound (105MB WRITE_SIZE for a
// 6.4MB ebuf; 0.91 TB/s scattered-line ceiling). Replaced the whole CSR build
// (count_deg + 3 scans + fill, ~160us) with a two-level bucket sort:
//   binA: bin edges by dst>>9 into 196 buckets, LDS histogram + run
//         reservation -> coalesced packed writes ((dstlow<<17)|src).
//   bucketscan: tiny exclusive scan of bucket totals.
//   binB: one block per bucket: LDS histogram (=degree) -> rowptr+dinv,
//         then scatter src ids within a ~32KB L2-resident window.
// Gather/GEMM kernels unchanged from round 5.

typedef __attribute__((ext_vector_type(8))) short bf16x8;   // 8 bf16 = 4 VGPRs
typedef __attribute__((ext_vector_type(4))) float f32x4;    // MFMA C/D

constexpr int NN = 100000;   // nodes
constexpr int NF = 512;      // input feats
constexpr int NH = 64;       // hidden
constexpr int NC = 40;       // classes
constexpr int NE = 1600000;  // edges

constexpr int NBUCK = 196;     // ceil(NN/512): bucket = dst >> 9
constexpr int CAP   = 12288;   // staging capacity/bucket (mean 8163, +45 sigma)
constexpr int ABLK  = 256;     // binA blocks
constexpr int CHUNK = NE / ABLK;  // 6250 edges/block (exact)

// ---- ws layout (byte offsets) ----
constexpr size_t OFF_DINV   = 0;           // float[NN]
constexpr size_t OFF_ROWPTR = 524288;      // int[NN+1]
constexpr size_t OFF_GCUR   = 1048576;     // int[256] bucket cursors/totals
constexpr size_t OFF_GOFS   = 1049600;     // int[256] bucket base offsets
constexpr size_t OFF_W1BF   = 1576960;     // bf16[64*512] = 64KB
constexpr size_t OFF_W2BF   = 1642496;     // bf16[40*64]
constexpr size_t OFF_EBUF   = 2097152;     // int[NE] CSR src ids, 6.4MB
constexpr size_t OFF_H1     = 9437184;     // bf16[NN*64] = 12.8MB (h2s reuses)
constexpr size_t OFF_R1     = 23068672;    // bf16[NN*64] = 12.8MB
// staging int[NBUCK*CAP] = 9.63MB ALIASES h1s/r1 region (dead during CSR build)
constexpr size_t OFF_STAGE  = OFF_H1;

// fp32 -> bf16 fragment helpers
__device__ inline short f2bs(float f) {
    union { __hip_bfloat16 h; short s; } u;
    u.h = __float2bfloat16(f);
    return u.s;
}
__device__ inline bf16x8 cvt8(const float* __restrict__ p) {
    bf16x8 r;
#pragma unroll
    for (int i = 0; i < 8; ++i) r[i] = f2bs(p[i]);
    return r;
}

// ---------------- W1/W2 fp32 -> bf16 (once) + zero bucket cursors ----------
__global__ __launch_bounds__(256) void k_cvtw(const float* __restrict__ W1,
                                              const float* __restrict__ W2,
                                              __hip_bfloat16* __restrict__ W1bf,
                                              __hip_bfloat16* __restrict__ W2bf,
                                              int* __restrict__ gcur) {
    int i = blockIdx.x * 256 + threadIdx.x;
    if (i < NH * NF) W1bf[i] = __float2bfloat16(W1[i]);
    int j = i - NH * NF;
    if (j >= 0 && j < NC * NH) W2bf[j] = __float2bfloat16(W2[j]);
    if (i < 256) gcur[i] = 0;
}

// ---------------- binA: bucket edges by dst>>9, coalesced packed writes ----
__global__ __launch_bounds__(256) void k_binA(const int* __restrict__ src,
                                              const int* __restrict__ dst,
                                              int* __restrict__ gcur,
                                              int* __restrict__ staging) {
    __shared__ int cnt[NBUCK];
    __shared__ int base[NBUCK];
    __shared__ int cur[NBUCK];
    const int t = threadIdx.x;
    const int e0 = blockIdx.x * CHUNK;
    for (int i = t; i < NBUCK; i += 256) { cnt[i] = 0; cur[i] = 0; }
    __syncthreads();
    for (int i = t; i < CHUNK; i += 256)
        atomicAdd(&cnt[dst[e0 + i] >> 9], 1);
    __syncthreads();
    for (int i = t; i < NBUCK; i += 256)
        base[i] = atomicAdd(&gcur[i], cnt[i]);   // reserve contiguous run
    __syncthreads();
    for (int i = t; i < CHUNK; i += 256) {
        int e = e0 + i;
        int d = dst[e];
        int b = d >> 9;
        int r = atomicAdd(&cur[b], 1);
        int pos = base[b] + r;
        if (pos < CAP)                            // deterministic input: never trips
            staging[b * CAP + pos] = ((d & 511) << 17) | src[e];
    }
}

// ---------------- exclusive scan of bucket totals -> gofs ----------------
__global__ __launch_bounds__(256) void k_bucketscan(const int* __restrict__ gcur,
                                                    int* __restrict__ gofs,
                                                    int* __restrict__ rowptr) {
    __shared__ int s[256];
    int t = threadIdx.x;
    int v = (t < NBUCK) ? gcur[t] : 0;
    s[t] = v;
    __syncthreads();
    for (int off = 1; off < 256; off <<= 1) {
        int tv = (t >= off) ? s[t - off] : 0;
        __syncthreads();
        s[t] += tv;
        __syncthreads();
    }
    if (t < NBUCK) gofs[t] = s[t] - v;   // exclusive
    if (t == 0) rowptr[NN] = NE;
}

// ---------------- binB: per-bucket degree/rowptr/dinv + local CSR scatter ----
__global__ __launch_bounds__(512) void k_binB(const int* __restrict__ gcur,
                                              const int* __restrict__ gofs,
                                              const int* __restrict__ staging,
                                              int* __restrict__ rowptr,
                                              float* __restrict__ dinv,
                                              int* __restrict__ ebuf) {
    __shared__ int hist[512];
    __shared__ int s[512];
    __shared__ int cur[512];
    const int b = blockIdx.x, t = threadIdx.x;
    const int count = gcur[b];
    const int sbase = b * CAP;
    hist[t] = 0;
    __syncthreads();
    for (int i = t; i < count; i += 512)
        atomicAdd(&hist[staging[sbase + i] >> 17], 1);
    __syncthreads();
    int v = hist[t];
    s[t] = v;
    __syncthreads();
    for (int off = 1; off < 512; off <<= 1) {
        int tv = (t >= off) ? s[t - off] : 0;
        __syncthreads();
        s[t] += tv;
        __syncthreads();
    }
    const int excl = s[t] - v;           // local exclusive offset
    const int base = gofs[b];
    int n = b * 512 + t;
    if (n < NN) {
        rowptr[n] = base + excl;
        dinv[n] = rsqrtf((float)v + 1.0f);   // +1 = self-loop
    }
    cur[t] = excl;
    __syncthreads();
    for (int i = t; i < count; i += 512) {
        int pv = staging[sbase + i];
        int p = atomicAdd(&cur[pv >> 17], 1);
        ebuf[base + p] = pv & 0x1FFFF;   // src id
    }
}

// ---------------- GEMM1: h1s[NN,64] = (x @ W1^T) * dinv[row]  (bf16) ----
__global__ __launch_bounds__(256) void k_gemm1(const float* __restrict__ x,
                                               const __hip_bfloat16* __restrict__ W1bf,
                                               const float* __restrict__ dinv,
                                               __hip_bfloat16* __restrict__ h1s) {
    const int lane = threadIdx.x & 63;
    const int wave = blockIdx.x * 4 + (threadIdx.x >> 6);
    const int row0 = wave * 64;
    if (row0 >= NN) return;
    const int q = lane >> 4, m = lane & 15;

    f32x4 acc[4][4];
#pragma unroll
    for (int i = 0; i < 4; ++i)
#pragma unroll
        for (int j = 0; j < 4; ++j) acc[i][j] = (f32x4){0.f, 0.f, 0.f, 0.f};

    for (int k0 = 0; k0 < NF; k0 += 32) {
        bf16x8 bfr[4];
#pragma unroll
        for (int ot = 0; ot < 4; ++ot)
            bfr[ot] = *reinterpret_cast<const bf16x8*>(W1bf + (ot * 16 + m) * NF + k0 + q * 8);
#pragma unroll
        for (int mt = 0; mt < 4; ++mt) {
            int r = row0 + mt * 16 + m;
            if (r > NN - 1) r = NN - 1;  // tail clamp (store guarded)
            bf16x8 afr = cvt8(x + (size_t)r * NF + k0 + q * 8);
#pragma unroll
            for (int ot = 0; ot < 4; ++ot)
                acc[mt][ot] = __builtin_amdgcn_mfma_f32_16x16x32_bf16(afr, bfr[ot], acc[mt][ot], 0, 0, 0);
        }
    }

#pragma unroll
    for (int mt = 0; mt < 4; ++mt)
#pragma unroll
        for (int rr = 0; rr < 4; ++rr) {
            int row = row0 + mt * 16 + q * 4 + rr;
            if (row < NN) {
                float di = dinv[row];
#pragma unroll
                for (int ot = 0; ot < 4; ++ot)
                    h1s[row * NH + ot * 16 + m] = __float2bfloat16(acc[mt][ot][rr] * di);
            }
        }
}

// ---------------- gather1: r1[n] = relu(dn * (sum h1s[s] + h1s[n]) + b1) ----
__global__ __launch_bounds__(256) void k_gather1(const int* __restrict__ rowptr,
                                                 const int* __restrict__ ebuf,
                                                 const float* __restrict__ dinv,
                                                 const __hip_bfloat16* __restrict__ h1s,
                                                 const float* __restrict__ b1,
                                                 __hip_bfloat16* __restrict__ r1) {
    const int lane = threadIdx.x & 63;
    const int n = blockIdx.x * 4 + (threadIdx.x >> 6);
    if (n >= NN) return;
    const int beg = rowptr[n], end = rowptr[n + 1];
    float acc = 0.0f;
    int j = beg;
    for (; j + 8 <= end; j += 8) {
        int e0 = ebuf[j + 0], e1 = ebuf[j + 1], e2 = ebuf[j + 2], e3 = ebuf[j + 3];
        int e4 = ebuf[j + 4], e5 = ebuf[j + 5], e6 = ebuf[j + 6], e7 = ebuf[j + 7];
        float v0 = __bfloat162float(h1s[e0 * NH + lane]);
        float v1 = __bfloat162float(h1s[e1 * NH + lane]);
        float v2 = __bfloat162float(h1s[e2 * NH + lane]);
        float v3 = __bfloat162float(h1s[e3 * NH + lane]);
        float v4 = __bfloat162float(h1s[e4 * NH + lane]);
        float v5 = __bfloat162float(h1s[e5 * NH + lane]);
        float v6 = __bfloat162float(h1s[e6 * NH + lane]);
        float v7 = __bfloat162float(h1s[e7 * NH + lane]);
        acc += ((v0 + v1) + (v2 + v3)) + ((v4 + v5) + (v6 + v7));
    }
    for (; j < end; ++j)
        acc += __bfloat162float(h1s[ebuf[j] * NH + lane]);
    acc += __bfloat162float(h1s[n * NH + lane]);   // self-loop (pre-scaled)
    acc = acc * dinv[n] + b1[lane];
    r1[n * NH + lane] = __float2bfloat16(fmaxf(acc, 0.0f));
}

// ---------------- GEMM2: h2s[NN,40] = (r1 @ W2^T) * dinv[row]  (bf16) ----
__global__ __launch_bounds__(256) void k_gemm2(const __hip_bfloat16* __restrict__ r1,
                                               const __hip_bfloat16* __restrict__ W2bf,
                                               const float* __restrict__ dinv,
                                               __hip_bfloat16* __restrict__ h2s) {
    const int lane = threadIdx.x & 63;
    const int wave = blockIdx.x * 4 + (threadIdx.x >> 6);
    const int row0 = wave * 64;
    if (row0 >= NN) return;
    const int q = lane >> 4, m = lane & 15;

    f32x4 acc[4][3];
#pragma unroll
    for (int i = 0; i < 4; ++i)
#pragma unroll
        for (int j = 0; j < 3; ++j) acc[i][j] = (f32x4){0.f, 0.f, 0.f, 0.f};

#pragma unroll
    for (int k0 = 0; k0 < NH; k0 += 32) {
        bf16x8 bfr[3];
#pragma unroll
        for (int ot = 0; ot < 3; ++ot) {
            int o = ot * 16 + m;
            if (o > NC - 1) o = NC - 1;  // stay inside W2's 40 rows
            bfr[ot] = *reinterpret_cast<const bf16x8*>(W2bf + o * NH + k0 + q * 8);
        }
#pragma unroll
        for (int mt = 0; mt < 4; ++mt) {
            int r = row0 + mt * 16 + m;
            if (r > NN - 1) r = NN - 1;
            bf16x8 afr = *reinterpret_cast<const bf16x8*>(r1 + r * NH + k0 + q * 8);
#pragma unroll
            for (int ot = 0; ot < 3; ++ot)
                acc[mt][ot] = __builtin_amdgcn_mfma_f32_16x16x32_bf16(afr, bfr[ot], acc[mt][ot], 0, 0, 0);
        }
    }

#pragma unroll
    for (int mt = 0; mt < 4; ++mt)
#pragma unroll
        for (int rr = 0; rr < 4; ++rr) {
            int row = row0 + mt * 16 + q * 4 + rr;
            if (row < NN) {
                float di = dinv[row];
#pragma unroll
                for (int ot = 0; ot < 3; ++ot) {
                    int col = ot * 16 + m;
                    if (col < NC) h2s[row * NC + col] = __float2bfloat16(acc[mt][ot][rr] * di);
                }
            }
        }
}

// ---------------- gather2: out[n] = dn*(sum h2s[s] + h2s[n]) + b2 (fp32) ----
__global__ __launch_bounds__(256) void k_gather2(const int* __restrict__ rowptr,
                                                 const int* __restrict__ ebuf,
                                                 const float* __restrict__ dinv,
                                                 const __hip_bfloat16* __restrict__ h2s,
                                                 const float* __restrict__ b2,
                                                 float* __restrict__ out) {
    const int lane = threadIdx.x & 63;
    const int n = blockIdx.x * 4 + (threadIdx.x >> 6);
    if (n >= NN || lane >= NC) return;
    const int beg = rowptr[n], end = rowptr[n + 1];
    float acc = 0.0f;
    int j = beg;
    for (; j + 8 <= end; j += 8) {
        int e0 = ebuf[j + 0], e1 = ebuf[j + 1], e2 = ebuf[j + 2], e3 = ebuf[j + 3];
        int e4 = ebuf[j + 4], e5 = ebuf[j + 5], e6 = ebuf[j + 6], e7 = ebuf[j + 7];
        float v0 = __bfloat162float(h2s[e0 * NC + lane]);
        float v1 = __bfloat162float(h2s[e1 * NC + lane]);
        float v2 = __bfloat162float(h2s[e2 * NC + lane]);
        float v3 = __bfloat162float(h2s[e3 * NC + lane]);
        float v4 = __bfloat162float(h2s[e4 * NC + lane]);
        float v5 = __bfloat162float(h2s[e5 * NC + lane]);
        float v6 = __bfloat162float(h2s[e6 * NC + lane]);
        float v7 = __bfloat162float(h2s[e7 * NC + lane]);
        acc += ((v0 + v1) + (v2 + v3)) + ((v4 + v5) + (v6 + v7));
    }
    for (; j < end; ++j)
        acc += __bfloat162float(h2s[ebuf[j] * NC + lane]);
    acc += __bfloat162float(h2s[n * NC + lane]);   // self-loop (pre-scaled)
    out[n * NC + lane] = acc * dinv[n] + b2[lane];
}

extern "C" void kernel_launch(void* const* d_in, const int* in_sizes, int n_in,
                              void* d_out, int out_size, void* d_ws, size_t ws_size,
                              hipStream_t stream) {
    const float* x  = (const float*)d_in[0];
    const int*   ei = (const int*)d_in[1];
    const float* W1 = (const float*)d_in[2];
    const float* b1 = (const float*)d_in[3];
    const float* W2 = (const float*)d_in[4];
    const float* b2 = (const float*)d_in[5];
    const int* srcp = ei;        // edge_index[0]
    const int* dstp = ei + NE;   // edge_index[1]

    char* ws = (char*)d_ws;
    float*          dinv    = (float*)(ws + OFF_DINV);
    int*            rowptr  = (int*)(ws + OFF_ROWPTR);
    int*            gcur    = (int*)(ws + OFF_GCUR);
    int*            gofs    = (int*)(ws + OFF_GOFS);
    __hip_bfloat16* W1bf    = (__hip_bfloat16*)(ws + OFF_W1BF);
    __hip_bfloat16* W2bf    = (__hip_bfloat16*)(ws + OFF_W2BF);
    int*            ebuf    = (int*)(ws + OFF_EBUF);
    int*            staging = (int*)(ws + OFF_STAGE);          // aliases h1s/r1
    __hip_bfloat16* h1s     = (__hip_bfloat16*)(ws + OFF_H1);  // h2s reuses
    __hip_bfloat16* r1      = (__hip_bfloat16*)(ws + OFF_R1);

    // --- weights to bf16 + zero bucket cursors ---
    k_cvtw<<<(NH * NF + NC * NH + 255) / 256, 256, 0, stream>>>(W1, W2, W1bf, W2bf, gcur);

    // --- CSR build: two-level bucket sort (staging aliases h1s/r1, dead here) ---
    k_binA<<<ABLK, 256, 0, stream>>>(srcp, dstp, gcur, staging);
    k_bucketscan<<<1, 256, 0, stream>>>(gcur, gofs, rowptr);
    k_binB<<<NBUCK, 512, 0, stream>>>(gcur, gofs, staging, rowptr, dinv, ebuf);

    const int gemm_blocks = (NN + 255) / 256;   // 4 waves/block, 64 rows/wave
    const int node_blocks = (NN + 3) / 4;       // 4 waves/block, 1 node/wave

    // --- layer 1 ---
    k_gemm1<<<gemm_blocks, 256, 0, stream>>>(x, W1bf, dinv, h1s);
    k_gather1<<<node_blocks, 256, 0, stream>>>(rowptr, ebuf, dinv, h1s, b1, r1);

    // --- layer 2 (h2s reuses h1s's buffer) ---
    __hip_bfloat16* h2s = h1s;
    k_gemm2<<<gemm_blocks, 256, 0, stream>>>(r1, W2bf, dinv, h2s);
    k_gather2<<<node_blocks, 256, 0, stream>>>(rowptr, ebuf, dinv, h2s, b2,
                                               (float*)d_out);
}